// Round 7
// baseline (242.875 us; speedup 1.0000x reference)
//
#include <hip/hip_runtime.h>
#include <hip/hip_bf16.h>
#include <math.h>

// Problem constants
#define B_ 4
#define L_ 4096
#define E_ 1024
#define H_ 16
#define D_ 64
#define N_ 64          // B*H heads
#define D2_ 128        // feature dim 2*D
#define EPS_ 1e-6f

#define CH_ 16             // phase1 L-chunks
#define LC_ (L_ / CH_)     // 256 rows per phase1 block
#define ST_ 16             // rows per phase1 stage
#define NSTG_ 16           // stages per block

#define DANG_ 3.83495197e-4f  // 0.5*pi/L

typedef short short8 __attribute__((ext_vector_type(8)));
typedef float f32x4 __attribute__((ext_vector_type(4)));
typedef unsigned int u32;
typedef unsigned short u16;

static __device__ __forceinline__ u32 pack2bf(float a, float b) {
  union { __hip_bfloat16 h; u16 s; } x, y;
  x.h = __float2bfloat16(a);
  y.h = __float2bfloat16(b);
  return (u32)x.s | ((u32)y.s << 16);
}

static __device__ __forceinline__ short bf1(float a) {
  union { __hip_bfloat16 h; short s; } x;
  x.h = __float2bfloat16(a);
  return x.s;
}

// async 16B global -> LDS (wave-uniform LDS base + lane*16; global src per-lane)
static __device__ __forceinline__ void gld16(const void* g, void* l) {
  __builtin_amdgcn_global_load_lds(
      (const __attribute__((address_space(1))) unsigned int*)g,
      (__attribute__((address_space(3))) unsigned int*)l, 16, 0, 0);
}

#define BAR_() __builtin_amdgcn_s_barrier()
#define WAIT_LGKM0_()                                     \
  {                                                       \
    asm volatile("s_waitcnt lgkmcnt(0)" ::: "memory");    \
    __builtin_amdgcn_sched_barrier(0);                    \
  }
#define WAIT_VM4_()                                       \
  {                                                       \
    asm volatile("s_waitcnt vmcnt(4)" ::: "memory");      \
    __builtin_amdgcn_sched_barrier(0);                    \
  }
#define WAIT_VM0_()                                       \
  {                                                       \
    asm volatile("s_waitcnt vmcnt(0)" ::: "memory");      \
    __builtin_amdgcn_sched_barrier(0);                    \
  }

// ---------------------------------------------------------------------------
// Phase 1 (MFMA): partial kv[d][m] = sum_l k_[l][d] * v[l][m], ksum[d]=sum k_
// HEAD-QUAD blocks: each block reads 1024B-contiguous row segments (4 heads).
// 256 blocks (1/CU), 512 threads (8 waves): wave w -> head w>>1, d-half w&1.
// 16-row stages, double-buffered raw f32 LDS via global_load_lds (XOR-
// swizzled global source, both-sides rule). vmcnt(4) before 2nd pack
// (stage S+1 landed) and at group end (S+2 landed); vmcnt(0) only at tail.
// ksum via ones-column B-fragment.
// ---------------------------------------------------------------------------
__global__ __launch_bounds__(512, 2) void phase1_mfma(
    const float* __restrict__ k, const float* __restrict__ v,
    const float* __restrict__ mask,
    float* __restrict__ part_kv, float* __restrict__ part_ks) {
  __shared__ __align__(16) float kraw[2][ST_ * 256];  // 2 x 16 KB
  __shared__ __align__(16) float vraw[2][ST_ * 256];  // 2 x 16 KB
  __shared__ __align__(16) u16 ka[4 * D2_ * 36];      // 36 KB (4 heads)
  __shared__ __align__(16) u16 vt[4 * D_ * 36];       // 18 KB
  __shared__ float msh[LC_];                          // 1 KB

  const int bid = blockIdx.x;
  const int p = bid & 15;           // head-quad 0..15
  const int ch = bid >> 4;          // 0..15
  const int b = p >> 2;
  const int hcol0 = (p & 3) * 256;  // f32 col of quad segment within E
  const int t = threadIdx.x;
  const int wv = t >> 6;            // 0..7
  const int lane = t & 63;
  const int c_lo = lane & 15;       // frag row
  const int lp = (lane >> 4) & 3;   // k-octet
  const int l0 = ch * LC_;

  // MFMA wave mapping
  const int hq = wv >> 1;           // head within quad
  const int dh = wv & 1;            // d-half (0: d<64, 1: d>=64)

  // pack-thread mapping (512 threads: 128 per head)
  const int hh = t >> 7;            // head within quad (pack role)
  const int tt = t & 127;
  const int lp2h = tt >> 4;         // row-pair within stage 0..7
  const int dg = tt & 15;           // d-group 0..15

  u32* ka32 = (u32*)ka;
  u32* vt32 = (u32*)vt;

  f32x4 acc[4][4];                  // [dt][mt]
#pragma unroll
  for (int i = 0; i < 4; ++i)
#pragma unroll
    for (int j = 0; j < 4; ++j) acc[i][j] = (f32x4)0.f;
  f32x4 acc5[4];                    // [dt] ksum
#pragma unroll
  for (int i = 0; i < 4; ++i) acc5[i] = (f32x4)0.f;

  // ones B-fragment: column m=0 all-ones
  short8 bones = {0, 0, 0, 0, 0, 0, 0, 0};
  if (c_lo == 0) {
#pragma unroll
    for (int j = 0; j < 8; ++j) bones[j] = (short)0x3F80;
  }

// issue one 16-row stage of raw k,v (4 gld16/wave). Each gld16 covers ONE
// full 1024B row segment. Source granule XOR-swizzled by row index.
#define P1_GLD(S, BUF)                                                       \
  do {                                                                       \
    _Pragma("unroll") for (int j_ = 0; j_ < 2; ++j_) {                       \
      const int r_ = 2 * wv + j_;                                            \
      const size_t gs_ = (size_t)(b * L_ + l0 + (S) * ST_ + r_) * E_ +       \
                         hcol0 + ((lane ^ r_) << 2);                         \
      gld16(k + gs_, &kraw[BUF][r_ * 256]);                                  \
      gld16(v + gs_, &vraw[BUF][r_ * 256]);                                  \
    }                                                                        \
  } while (0)

// pack one 16-row stage (half of a K=32 tile) for this thread's head.
#define P1_PACK(S, BUF)                                                      \
  do {                                                                       \
    const int la_ = 2 * lp2h, lb_ = la_ + 1;                                 \
    const float m0_ = msh[(S) * ST_ + la_];                                  \
    const float m1_ = msh[(S) * ST_ + lb_];                                  \
    const int lga_ = l0 + (S) * ST_ + la_;                                   \
    float s0_, c0_, s1_, c1_;                                                \
    __sincosf((float)(lga_ + 1) * DANG_, &s0_, &c0_);                        \
    __sincosf((float)(lga_ + 2) * DANG_, &s1_, &c1_);                        \
    const int li_ = ((S) & 1) * 8 + lp2h;                                    \
    _Pragma("unroll") for (int dj_ = 0; dj_ < 4; ++dj_) {                    \
      const int d_ = dg + 16 * dj_;                                          \
      const int c_ = hh * 64 + d_;                                           \
      const int G_ = c_ >> 2, su_ = c_ & 3;                                  \
      const float k0_ = kraw[BUF][la_ * 256 + ((G_ ^ la_) << 2) + su_];      \
      const float k1_ = kraw[BUF][lb_ * 256 + ((G_ ^ lb_) << 2) + su_];      \
      const float v0_ = vraw[BUF][la_ * 256 + ((G_ ^ la_) << 2) + su_];      \
      const float v1_ = vraw[BUF][lb_ * 256 + ((G_ ^ lb_) << 2) + su_];      \
      const float kr0_ = fmaxf(k0_, 0.f) * m0_;                              \
      const float kr1_ = fmaxf(k1_, 0.f) * m1_;                              \
      ka32[hh * 2304 + d_ * 18 + li_] = pack2bf(kr0_ * s0_, kr1_ * s1_);     \
      ka32[hh * 2304 + (d_ + 64) * 18 + li_] =                               \
          pack2bf(kr0_ * c0_, kr1_ * c1_);                                   \
      vt32[hh * 1152 + d_ * 18 + li_] = pack2bf(v0_ * m0_, v1_ * m1_);       \
    }                                                                        \
  } while (0)

// MFMA one K=32 step: wave -> (head hq, d-half dh): 16 real + 4 ones
#define P1_MMA()                                                             \
  do {                                                                       \
    short8 af_[4], bf_[4];                                                   \
    _Pragma("unroll") for (int dt_ = 0; dt_ < 4; ++dt_)                      \
        af_[dt_] = *(const short8*)                                          \
            &ka[hq * 4608 + (dh * 64 + dt_ * 16 + c_lo) * 36 + lp * 8];      \
    _Pragma("unroll") for (int mt_ = 0; mt_ < 4; ++mt_)                      \
        bf_[mt_] = *(const short8*)                                          \
            &vt[hq * 2304 + (mt_ * 16 + c_lo) * 36 + lp * 8];                \
    _Pragma("unroll") for (int dt_ = 0; dt_ < 4; ++dt_) {                    \
      _Pragma("unroll") for (int mt_ = 0; mt_ < 4; ++mt_)                    \
          acc[dt_][mt_] = __builtin_amdgcn_mfma_f32_16x16x32_bf16(           \
              af_[dt_], bf_[mt_], acc[dt_][mt_], 0, 0, 0);                   \
      acc5[dt_] = __builtin_amdgcn_mfma_f32_16x16x32_bf16(af_[dt_], bones,   \
                                                          acc5[dt_], 0, 0,   \
                                                          0);                \
    }                                                                        \
  } while (0)

// 2-stage group (S even), double-buffered: bufs S%2, (S+1)%2.
// MID: 1 = issue GLD(S+2); END: 1 = issue GLD(S+3). VMID: 4|0.
#define P1_GROUP(S, MID, END, VMID)                                          \
  do {                                                                       \
    P1_PACK((S), (S) % 2);                                                   \
    BAR_(); /* buf S%2 fully read by all waves */                            \
    if (MID) P1_GLD((S) + 2, (S) % 2);                                       \
    if ((VMID) == 4) { WAIT_VM4_(); }                                        \
    else { WAIT_VM0_(); }                                                    \
    P1_PACK((S) + 1, ((S) + 1) % 2);                                         \
    WAIT_LGKM0_();                                                           \
    BAR_(); /* tiles complete */                                             \
    if (END) P1_GLD((S) + 3, ((S) + 1) % 2);                                 \
    P1_MMA();                                                                \
    if (END) { WAIT_VM4_(); }                                                \
    BAR_(); /* tiles consumed; next raw landed */                            \
  } while (0)

  // prologue: mask (wave0, 1 inst) + stages 0,1
  if (wv == 0) gld16(mask + (size_t)b * L_ + l0 + lane * 4, msh);
  P1_GLD(0, 0);
  P1_GLD(1, 1);
  WAIT_VM4_();  // mask + stage0 landed (in-order); stage1's 4 in flight
  BAR_();

  P1_GROUP(0, 1, 1, 4);
  P1_GROUP(2, 1, 1, 4);
  P1_GROUP(4, 1, 1, 4);
  P1_GROUP(6, 1, 1, 4);
  P1_GROUP(8, 1, 1, 4);
  P1_GROUP(10, 1, 1, 4);
  P1_GROUP(12, 1, 1, 4);   // issues 14,15; end vm4 lands 14
  P1_GROUP(14, 0, 0, 0);   // mid vm0 drains 15; final MMA

  // write partial kv (fp32). C layout: row(d)=lp*4+r, col(m)=c_lo
  const int n = 4 * p + hq;
  const size_t pbase = (size_t)(ch * N_ + n) * (D2_ * D_);
#pragma unroll
  for (int dt = 0; dt < 4; ++dt) {
    const int d = dh * 64 + dt * 16 + lp * 4;
#pragma unroll
    for (int mt = 0; mt < 4; ++mt) {
      const int mcol = mt * 16 + c_lo;
#pragma unroll
      for (int r = 0; r < 4; ++r)
        part_kv[pbase + (size_t)(d + r) * D_ + mcol] = acc[dt][mt][r];
    }
  }
  if (c_lo == 0) {
#pragma unroll
    for (int dt = 0; dt < 4; ++dt)
#pragma unroll
      for (int r = 0; r < 4; ++r)
        part_ks[(size_t)(ch * N_ + n) * D2_ + dh * 64 + dt * 16 + lp * 4 + r] =
            acc5[dt][r];
  }
}

// ---------------------------------------------------------------------------
// Reduce: sum chunk partials; emit kvT[n][m][d] bf16 + ksum fp32.
// 512 blocks (8 e-slices per head), f32x4 loads, small LDS transpose.
// ---------------------------------------------------------------------------
__global__ __launch_bounds__(256) void reduce_t(
    const float* __restrict__ part_kv, const float* __restrict__ part_ks,
    u16* __restrict__ kvt, float* __restrict__ ks) {
  __shared__ __align__(16) float tsh[16 * 68];
  const int bid = blockIdx.x;
  const int n = bid >> 3;
  const int sl = bid & 7;
  const int t = threadIdx.x;

  const int e0 = sl * 1024 + t * 4;  // covers d=sl*16..+16, m=0..63
  f32x4 s = (f32x4)0.f;
#pragma unroll
  for (int cc = 0; cc < CH_; ++cc)
    s += *(const f32x4*)&part_kv[(size_t)(cc * N_ + n) * (D2_ * D_) + e0];
  *(f32x4*)&tsh[(t >> 4) * 68 + (t & 15) * 4] = s;

  if (sl == 0 && t < D2_) {
    float ss = 0.f;
#pragma unroll
    for (int cc = 0; cc < CH_; ++cc)
      ss += part_ks[(size_t)(cc * N_ + n) * D2_ + t];
    ks[n * D2_ + t] = ss;
  }
  __syncthreads();

  // transpose out: thread -> m = t>>2, 4 consecutive d
  const int m = t >> 2;
  const int d4 = (t & 3) * 4;
  const u32 lo = pack2bf(tsh[(d4 + 0) * 68 + m], tsh[(d4 + 1) * 68 + m]);
  const u32 hi = pack2bf(tsh[(d4 + 2) * 68 + m], tsh[(d4 + 3) * 68 + m]);
  uint2 pk; pk.x = lo; pk.y = hi;
  *(uint2*)&kvt[(size_t)n * (D2_ * D_) + (size_t)m * D2_ + sl * 16 + d4] = pk;
}

// ---------------------------------------------------------------------------
// Phase 2 (MFMA): out[l][m] = z[l] * sum_d q_[l][d] * kv[d][m]
// Two 64-row l-chunks per block; kvt staged ONCE per block. All staging via
// global_load_lds width=16 (12 insts/wave), one barrier per block. Granules
// XOR-swizzled on the GLOBAL source and on the LDS reads (both-sides rule).
// z via 5th B-fragment whose column 0 is ksum.
// ---------------------------------------------------------------------------
__global__ __launch_bounds__(256, 3) void phase2_mfma(
    const float* __restrict__ q, const u16* __restrict__ kvt,
    const float* __restrict__ ks, float* __restrict__ out) {
  __shared__ __align__(16) float qsh[2 * 64 * 64];  // 32KB raw q, 2 chunks
  __shared__ __align__(16) u16 kbsh[64 * 128];      // 16KB kvt rows

  const int bid = blockIdx.x;
  const int n = bid & 63;
  const int g2 = bid >> 6;          // 0..31
  const int b = n >> 4, h = n & 15;
  const int t = threadIdx.x;
  const int wv = t >> 6, lane = t & 63;
  const int c_lo = lane & 15, quad = lane >> 4;
  const int l0 = g2 * 128;

  // ---- async staging: wave wv owns rows [wv*16, wv*16+16) of each tile ----
  const float* qbase = q + (size_t)(b * L_ + l0) * E_ + h * 64;
  const u16* kvbase = kvt + (size_t)n * (D2_ * D_);
  const int rsub = lane >> 4;  // row within one 1KB instruction
  const int g = lane & 15;     // physical 16B granule within row
#pragma unroll
  for (int j = 0; j < 4; ++j) {
    const int r = wv * 16 + j * 4 + rsub;
    const int sw = (g ^ (r & 15));
    gld16(kvbase + (size_t)r * D2_ + (sw << 3),
          kbsh + (wv * 16 + j * 4) * 128);
    gld16(qbase + (size_t)r * E_ + (sw << 2),
          qsh + (wv * 16 + j * 4) * 64);
    gld16(qbase + (size_t)(64 + r) * E_ + (sw << 2),
          qsh + 4096 + (wv * 16 + j * 4) * 64);
  }

  // ---- ksum B-fragments (register path, col 0 = ksum) ----
  const float* ksn = ks + n * D2_;
  short8 bks[4];
#pragma unroll
  for (int kk = 0; kk < 4; ++kk) {
    const f32x4 ka_ = *(const f32x4*)(ksn + kk * 32 + quad * 8);
    const f32x4 kb_ = *(const f32x4*)(ksn + kk * 32 + quad * 8 + 4);
    short8 tt = {0, 0, 0, 0, 0, 0, 0, 0};
    if (c_lo == 0) {
#pragma unroll
      for (int j = 0; j < 4; ++j) {
        tt[j] = bf1(ka_[j]);
        tt[j + 4] = bf1(kb_[j]);
      }
    }
    bks[kk] = tt;
  }

  __syncthreads();  // drains vmcnt(0): all global_load_lds landed

#pragma unroll
  for (int cc = 0; cc < 2; ++cc) {
    const int row = wv * 16 + c_lo;  // A-row within chunk
    const int glr = l0 + cc * 64 + row;
    float sv, cv;
    __sincosf((float)(glr + 1) * DANG_, &sv, &cv);

    // A-fragments from raw q LDS (swizzled reads)
    const float* qrow = qsh + cc * 4096 + row * 64;
    const int sw = row & 15;
    const f32x4 a0 = *(const f32x4*)(qrow + (((2 * quad) ^ sw) << 2));
    const f32x4 a1 = *(const f32x4*)(qrow + (((2 * quad + 1) ^ sw) << 2));
    const f32x4 a2 = *(const f32x4*)(qrow + (((8 + 2 * quad) ^ sw) << 2));
    const f32x4 a3 = *(const f32x4*)(qrow + (((9 + 2 * quad) ^ sw) << 2));

    short8 af[4];
#pragma unroll
    for (int j = 0; j < 4; ++j) {
      const float x0 = fmaxf(a0[j], 0.f);
      const float x1 = fmaxf(a1[j], 0.f);
      const float x2 = fmaxf(a2[j], 0.f);
      const float x3 = fmaxf(a3[j], 0.f);
      af[0][j] = bf1(x0 * sv); af[0][j + 4] = bf1(x1 * sv);
      af[1][j] = bf1(x2 * sv); af[1][j + 4] = bf1(x3 * sv);
      af[2][j] = bf1(x0 * cv); af[2][j + 4] = bf1(x1 * cv);
      af[3][j] = bf1(x2 * cv); af[3][j + 4] = bf1(x3 * cv);
    }

    f32x4 acc[4];
#pragma unroll
    for (int mt = 0; mt < 4; ++mt) acc[mt] = (f32x4)0.f;
    f32x4 acc5 = (f32x4)0.f;

#pragma unroll
    for (int kk = 0; kk < 4; ++kk) {
#pragma unroll
      for (int mt = 0; mt < 4; ++mt) {
        const int m = mt * 16 + c_lo;
        const short8 bfr = *(const short8*)
            &kbsh[m * 128 + (((kk * 4 + quad) ^ (m & 15)) << 3)];
        acc[mt] =
            __builtin_amdgcn_mfma_f32_16x16x32_bf16(af[kk], bfr, acc[mt], 0, 0, 0);
      }
      acc5 = __builtin_amdgcn_mfma_f32_16x16x32_bf16(af[kk], bks[kk], acc5, 0, 0, 0);
    }

    // epilogue: z from acc5 col 0 (lane quad*16), scale, store
#pragma unroll
    for (int r = 0; r < 4; ++r) {
      const float den = __shfl(acc5[r], quad * 16);
      const float z = 1.f / fmaxf(den, EPS_);
      const int gl = l0 + cc * 64 + wv * 16 + quad * 4 + r;
      const size_t ob = (size_t)n * (L_ * D_) + (size_t)gl * D_;
#pragma unroll
      for (int mt = 0; mt < 4; ++mt)
        out[ob + mt * 16 + c_lo] = acc[mt][r] * z;
    }
  }
}

// ---------------------------------------------------------------------------
extern "C" void kernel_launch(void* const* d_in, const int* in_sizes, int n_in,
                              void* d_out, int out_size, void* d_ws,
                              size_t ws_size, hipStream_t stream) {
  const float* q = (const float*)d_in[0];
  const float* k = (const float*)d_in[1];
  const float* v = (const float*)d_in[2];
  const float* mask = (const float*)d_in[3];
  float* out = (float*)d_out;

  float* part_kv = (float*)d_ws;                             // 16*64*8192 f32 = 33.5 MB
  float* part_ks = part_kv + (size_t)CH_ * N_ * D2_ * D_;    // 16*64*128 f32
  u16* kvt = (u16*)(part_ks + (size_t)CH_ * N_ * D2_);       // 64*8192 bf16 = 1 MB
  float* ks = (float*)(kvt + (size_t)N_ * D2_ * D_);         // 64*128 f32

  phase1_mfma<<<dim3(CH_ * 16), dim3(512), 0, stream>>>(k, v, mask, part_kv, part_ks);
  reduce_t<<<dim3(N_ * 8), dim3(256), 0, stream>>>(part_kv, part_ks, kvt, ks);
  phase2_mfma<<<dim3(N_ * 32), dim3(256), 0, stream>>>(q, kvt, ks, out);
}